// Round 1
// baseline (2453.782 us; speedup 1.0000x reference)
//
#include <hip/hip_runtime.h>
#include <hip/hip_bf16.h>
#include <stdint.h>

#define NATOMS 200000
#define NBONDS 300000
#define NEDGE  600000
#define DF     128
#define NBUCK  32
#define EPS    1e-5f

typedef __attribute__((ext_vector_type(8))) short bf16x8;
typedef __attribute__((ext_vector_type(4))) float f32x4;
typedef unsigned short u16;

__device__ __forceinline__ short f2b(float f) {
  union { float f; uint32_t u; } v; v.f = f;
  uint32_t r = v.u + 0x7fffu + ((v.u >> 16) & 1u);
  return (short)(r >> 16);
}

__device__ __forceinline__ bf16x8 zero8() {
  bf16x8 z;
#pragma unroll
  for (int i = 0; i < 8; ++i) z[i] = 0;
  return z;
}

// ---- convert weights to bf16 ----
__global__ void k_prep(const float* __restrict__ W, const float* __restrict__ Wr,
                       u16* __restrict__ Wb, u16* __restrict__ Wrb) {
  int i = blockIdx.x * blockDim.x + threadIdx.x;
  if (i < DF * DF) {
    Wb[i]  = (u16)f2b(W[i]);
    Wrb[i] = (u16)f2b(Wr[i]);
  }
}

// ---- scatter-add x rows into d_out (agg buffers), count degrees ----
__global__ void k_scatter(const float* __restrict__ xa, const float* __restrict__ xb,
                          const int* __restrict__ ab, const int* __restrict__ ba,
                          float* __restrict__ out,
                          int* __restrict__ ca, int* __restrict__ cb) {
  int gid = blockIdx.x * blockDim.x + threadIdx.x;
  int c = gid & 31;           // 32 lanes per edge, float4 each
  int slot = gid >> 5;
  int nslots = (gridDim.x * blockDim.x) >> 5;
  for (int e = slot; e < 2 * NEDGE; e += nslots) {
    if (e < NEDGE) {
      int s = ab[e], d = ab[NEDGE + e];
      const float4 v = *(const float4*)(xa + (size_t)s * DF + c * 4);
      float* o = out + (size_t)NATOMS * DF + (size_t)d * DF + c * 4;
      atomicAdd(o + 0, v.x); atomicAdd(o + 1, v.y);
      atomicAdd(o + 2, v.z); atomicAdd(o + 3, v.w);
      if (c == 0) atomicAdd(cb + d, 1);
    } else {
      int e2 = e - NEDGE;
      int s = ba[e2], d = ba[NEDGE + e2];
      const float4 v = *(const float4*)(xb + (size_t)s * DF + c * 4);
      float* o = out + (size_t)d * DF + c * 4;
      atomicAdd(o + 0, v.x); atomicAdd(o + 1, v.y);
      atomicAdd(o + 2, v.z); atomicAdd(o + 3, v.w);
      if (c == 0) atomicAdd(ca + d, 1);
    }
  }
}

// ---- fused: out_row = agg@W^T + cnt*b + relu(x@Wr^T + br); BN partial stats ----
__global__ __launch_bounds__(256) void k_gemm(
    const float* __restrict__ xa, const float* __restrict__ xb,
    float* __restrict__ out,
    const int* __restrict__ ca, const int* __restrict__ cb,
    const u16* __restrict__ Wb, const u16* __restrict__ Wrb,
    const float* __restrict__ bb, const float* __restrict__ brb,
    float* __restrict__ stats) {
  __shared__ u16 Wl[DF * DF];    // 32KB, XOR-swizzled by row&7 at 16B granularity
  __shared__ u16 Wrl[DF * DF];   // 32KB

  // stage weights (swizzled so ds_read_b128 of a 16-row column slice spreads banks)
  {
    const uint4* gw  = (const uint4*)Wb;
    const uint4* gwr = (const uint4*)Wrb;
    uint4* lw  = (uint4*)Wl;
    uint4* lwr = (uint4*)Wrl;
    for (int i = threadIdx.x; i < DF * DF / 8; i += 256) {
      int row = i >> 4, c8 = i & 15;
      int dst = (row << 4) | (c8 ^ (row & 7));
      lw[dst]  = gw[i];
      lwr[dst] = gwr[i];
    }
  }
  __syncthreads();

  int typ, base, nrows;
  const float* x; const int* cnt; float* o;
  if ((int)blockIdx.x < NATOMS / 64) {
    typ = 0; base = blockIdx.x * 64; nrows = NATOMS;
    x = xa; cnt = ca; o = out;
  } else {
    typ = 1; base = ((int)blockIdx.x - NATOMS / 64) * 64; nrows = NBONDS;
    x = xb; cnt = cb; o = out + (size_t)NATOMS * DF;
  }

  int lane = threadIdx.x & 63;
  int wv = threadIdx.x >> 6;     // wave 0..3, each owns 16 rows
  int r16 = lane & 15;
  int kq = lane >> 4;            // 0..3
  int arow = base + wv * 16 + r16;
  bool avalid = arow < nrows;

  f32x4 accW[8], accR[8];
#pragma unroll
  for (int t = 0; t < 8; ++t) {
#pragma unroll
    for (int r = 0; r < 4; ++r) { accW[t][r] = 0.f; accR[t][r] = 0.f; }
  }

  const float* aggp = o + (size_t)arow * DF + kq * 8;
  const float* xp   = x + (size_t)arow * DF + kq * 8;

#pragma unroll
  for (int kk = 0; kk < 4; ++kk) {
    bf16x8 afA = zero8(), afX = zero8();
    if (avalid) {
      const float4 a0 = *(const float4*)(aggp + kk * 32);
      const float4 a1 = *(const float4*)(aggp + kk * 32 + 4);
      const float4 x0 = *(const float4*)(xp + kk * 32);
      const float4 x1 = *(const float4*)(xp + kk * 32 + 4);
      afA[0] = f2b(a0.x); afA[1] = f2b(a0.y); afA[2] = f2b(a0.z); afA[3] = f2b(a0.w);
      afA[4] = f2b(a1.x); afA[5] = f2b(a1.y); afA[6] = f2b(a1.z); afA[7] = f2b(a1.w);
      afX[0] = f2b(x0.x); afX[1] = f2b(x0.y); afX[2] = f2b(x0.z); afX[3] = f2b(x0.w);
      afX[4] = f2b(x1.x); afX[5] = f2b(x1.y); afX[6] = f2b(x1.z); afX[7] = f2b(x1.w);
    }
    int c8 = kk * 4 + kq;
#pragma unroll
    for (int t = 0; t < 8; ++t) {
      int rw = t * 16 + r16;
      int chunk = (rw << 4) | (c8 ^ (rw & 7));
      bf16x8 bW = *(const bf16x8*)(Wl + chunk * 8);
      bf16x8 bR = *(const bf16x8*)(Wrl + chunk * 8);
      accW[t] = __builtin_amdgcn_mfma_f32_16x16x32_bf16(afA, bW, accW[t], 0, 0, 0);
      accR[t] = __builtin_amdgcn_mfma_f32_16x16x32_bf16(afX, bR, accR[t], 0, 0, 0);
    }
  }

  // epilogue: C/D layout col = lane&15, row = (lane>>4)*4 + reg   [m89-verified]
  int orow0 = base + wv * 16 + kq * 4;
  float cf[4];
#pragma unroll
  for (int r = 0; r < 4; ++r) {
    int rr = orow0 + r;
    cf[r] = (rr < nrows) ? (float)cnt[rr] : 0.f;
  }

  float lsum[8], lss[8];
#pragma unroll
  for (int t = 0; t < 8; ++t) {
    int feat = t * 16 + r16;
    float bv = bb[feat], brv = brb[feat];
    float ts = 0.f, tss = 0.f;
#pragma unroll
    for (int r = 0; r < 4; ++r) {
      int rr = orow0 + r;
      if (rr < nrows) {
        float g = accW[t][r] + cf[r] * bv + fmaxf(accR[t][r] + brv, 0.f);
        o[(size_t)rr * DF + feat] = g;
        ts += g; tss += g * g;
      }
    }
    lsum[t] = ts; lss[t] = tss;
  }

  // weights no longer needed: reuse LDS for BN partial reduction
  __syncthreads();
  float* s_sum = (float*)Wl;
  float* s_ss  = ((float*)Wl) + DF;
  if (threadIdx.x < DF) { s_sum[threadIdx.x] = 0.f; s_ss[threadIdx.x] = 0.f; }
  __syncthreads();
#pragma unroll
  for (int t = 0; t < 8; ++t) {
    float s = lsum[t], q = lss[t];
    s += __shfl_xor(s, 16); q += __shfl_xor(q, 16);
    s += __shfl_xor(s, 32); q += __shfl_xor(q, 32);
    if (kq == 0) {   // lanes 0..15 hold the reduced values
      atomicAdd(&s_sum[t * 16 + r16], s);
      atomicAdd(&s_ss[t * 16 + r16], q);
    }
  }
  __syncthreads();
  if (threadIdx.x < DF) {
    float* dstS = stats + ((size_t)(blockIdx.x & (NBUCK - 1)) * 2 + typ) * 2 * DF;
    atomicAdd(dstS + threadIdx.x, s_sum[threadIdx.x]);
    atomicAdd(dstS + DF + threadIdx.x, s_ss[threadIdx.x]);
  }
}

// ---- finalize stats -> scale/shift per (type, feature) ----
__global__ void k_stats(const float* __restrict__ stats,
                        const float* __restrict__ ga, const float* __restrict__ bea,
                        const float* __restrict__ gb, const float* __restrict__ beb,
                        float* __restrict__ scale, float* __restrict__ shift) {
  int tid = threadIdx.x;
  if (tid < 2 * DF) {
    int t = tid >> 7, f = tid & (DF - 1);
    float S = 0.f, SS = 0.f;
    for (int bk = 0; bk < NBUCK; ++bk) {
      const float* p = stats + ((size_t)bk * 2 + t) * 2 * DF;
      S += p[f]; SS += p[DF + f];
    }
    float n = t ? (float)NBONDS : (float)NATOMS;
    float mean = S / n;
    float var = SS / n - mean * mean;
    float rstd = rsqrtf(var + EPS);
    float g = t ? gb[f] : ga[f];
    float be = t ? beb[f] : bea[f];
    scale[tid] = rstd * g;
    shift[tid] = be - mean * rstd * g;
  }
}

// ---- in-place normalize ----
__global__ void k_norm(float* __restrict__ out, const float* __restrict__ scale,
                       const float* __restrict__ shift) {
  const size_t nv = (size_t)(NATOMS + NBONDS) * DF / 4;
  size_t stride = (size_t)gridDim.x * blockDim.x;
  for (size_t i = (size_t)blockIdx.x * blockDim.x + threadIdx.x; i < nv; i += stride) {
    size_t e = i * 4;
    int t = e >= (size_t)NATOMS * DF;
    int f = (int)(e & (DF - 1));
    const float* sc = scale + t * DF + f;
    const float* sh = shift + t * DF + f;
    float4 v = ((float4*)out)[i];
    v.x = fmaf(v.x, sc[0], sh[0]);
    v.y = fmaf(v.y, sc[1], sh[1]);
    v.z = fmaf(v.z, sc[2], sh[2]);
    v.w = fmaf(v.w, sc[3], sh[3]);
    ((float4*)out)[i] = v;
  }
}

extern "C" void kernel_launch(void* const* d_in, const int* in_sizes, int n_in,
                              void* d_out, int out_size, void* d_ws, size_t ws_size,
                              hipStream_t stream) {
  const float* xa  = (const float*)d_in[0];
  const float* xb  = (const float*)d_in[1];
  const int*   ab  = (const int*)d_in[2];
  const int*   ba  = (const int*)d_in[3];
  const float* W   = (const float*)d_in[4];
  const float* b   = (const float*)d_in[5];
  const float* Wr  = (const float*)d_in[6];
  const float* br  = (const float*)d_in[7];
  const float* ga  = (const float*)d_in[8];
  const float* bea = (const float*)d_in[9];
  const float* gb  = (const float*)d_in[10];
  const float* beb = (const float*)d_in[11];
  float* out = (float*)d_out;

  char* ws = (char*)d_ws;
  int*   ca    = (int*)ws;                   // 200000 * 4 = 800000 B
  int*   cb    = (int*)(ws + 800000);        // 300000 * 4 = 1200000 B
  float* stats = (float*)(ws + 2000000);     // 32*2*2*128*4 = 65536 B
  u16*   Wbf   = (u16*)(ws + 2065536);       // 32768 B
  u16*   Wrbf  = (u16*)(ws + 2098304);       // 32768 B
  float* scale = (float*)(ws + 2131072);     // 1024 B
  float* shift = (float*)(ws + 2132096);     // 1024 B

  hipMemsetAsync(d_out, 0, (size_t)(NATOMS + NBONDS) * DF * sizeof(float), stream);
  hipMemsetAsync(d_ws, 0, 2065536, stream);  // counts + stats

  k_prep<<<64, 256, 0, stream>>>(W, Wr, Wbf, Wrbf);
  k_scatter<<<4096, 256, 0, stream>>>(xa, xb, ab, ba, out, ca, cb);
  int nblk = NATOMS / 64 + (NBONDS + 63) / 64;  // 3125 + 4688
  k_gemm<<<nblk, 256, 0, stream>>>(xa, xb, out, ca, cb, Wbf, Wrbf, b, br, stats);
  k_stats<<<1, 256, 0, stream>>>(stats, ga, bea, gb, beb, scale, shift);
  k_norm<<<16384, 256, 0, stream>>>(out, scale, shift);
}

// Round 2
// 723.769 us; speedup vs baseline: 3.3903x; 3.3903x over previous
//
#include <hip/hip_runtime.h>
#include <hip/hip_bf16.h>
#include <stdint.h>

#define NATOMS 200000
#define NBONDS 300000
#define NEDGE  600000
#define NSEG   (NATOMS + NBONDS)   // 500000 combined dst rows
#define DF     128
#define NBUCK  32
#define EPS    1e-5f
#define SCHUNK 2048
#define NSBLK  ((NSEG + SCHUNK - 1) / SCHUNK)  // 245

typedef __attribute__((ext_vector_type(8))) short bf16x8;
typedef __attribute__((ext_vector_type(4))) float f32x4;
typedef unsigned short u16;

__device__ __forceinline__ short f2b(float f) {
  union { float f; uint32_t u; } v; v.f = f;
  uint32_t r = v.u + 0x7fffu + ((v.u >> 16) & 1u);
  return (short)(r >> 16);
}

__device__ __forceinline__ bf16x8 zero8() {
  bf16x8 z;
#pragma unroll
  for (int i = 0; i < 8; ++i) z[i] = 0;
  return z;
}

// ---- convert weights to bf16 ----
__global__ void k_prep(const float* __restrict__ W, const float* __restrict__ Wr,
                       u16* __restrict__ Wb, u16* __restrict__ Wrb) {
  int i = blockIdx.x * blockDim.x + threadIdx.x;
  if (i < DF * DF) {
    Wb[i]  = (u16)f2b(W[i]);
    Wrb[i] = (u16)f2b(Wr[i]);
  }
}

// ---- histogram of combined dst indices ----
__global__ void k_hist(const int* __restrict__ ab, const int* __restrict__ ba,
                       int* __restrict__ cnt) {
  int stride = gridDim.x * blockDim.x;
  for (int e = blockIdx.x * blockDim.x + threadIdx.x; e < 2 * NEDGE; e += stride) {
    int g;
    if (e < NEDGE) g = NATOMS + ab[NEDGE + e];      // ab edge -> bond dst
    else           g = ba[NEDGE + (e - NEDGE)];     // ba edge -> atom dst
    atomicAdd(cnt + g, 1);
  }
}

// ---- 3-phase exclusive scan of cnt[NSEG] -> off, cursor ----
__global__ void k_scanA(const int* __restrict__ cnt, int* __restrict__ bsum) {
  __shared__ int wsm[4];
  int t = threadIdx.x;
  int base = blockIdx.x * SCHUNK + t * 8;
  int s = 0;
#pragma unroll
  for (int j = 0; j < 8; ++j) { int i = base + j; if (i < NSEG) s += cnt[i]; }
  for (int d = 1; d < 64; d <<= 1) s += __shfl_xor(s, d);
  if ((t & 63) == 0) wsm[t >> 6] = s;
  __syncthreads();
  if (t == 0) bsum[blockIdx.x] = wsm[0] + wsm[1] + wsm[2] + wsm[3];
}

__global__ void k_scanB(const int* __restrict__ bsum, int* __restrict__ bbase) {
  __shared__ int wsm[4];
  int t = threadIdx.x;
  int lane = t & 63;
  int v = (t < NSBLK) ? bsum[t] : 0;
  int s = v;
  for (int d = 1; d < 64; d <<= 1) { int n = __shfl_up(s, d); if (lane >= d) s += n; }
  if (lane == 63) wsm[t >> 6] = s;
  __syncthreads();
  int wbase = 0;
  for (int w = 0; w < (t >> 6); ++w) wbase += wsm[w];
  if (t < NSBLK) bbase[t] = wbase + s - v;  // exclusive
}

__global__ void k_scanC(const int* __restrict__ cnt, const int* __restrict__ bbase,
                        int* __restrict__ off, int* __restrict__ cursor) {
  __shared__ int wsm[4];
  int t = threadIdx.x;
  int lane = t & 63, wv = t >> 6;
  int base = blockIdx.x * SCHUNK + t * 8;
  int v[8]; int ts = 0;
#pragma unroll
  for (int j = 0; j < 8; ++j) { int i = base + j; v[j] = (i < NSEG) ? cnt[i] : 0; ts += v[j]; }
  int s = ts;
  for (int d = 1; d < 64; d <<= 1) { int n = __shfl_up(s, d); if (lane >= d) s += n; }
  if (lane == 63) wsm[wv] = s;
  __syncthreads();
  int wbase = bbase[blockIdx.x];
  for (int w = 0; w < wv; ++w) wbase += wsm[w];
  int run = wbase + s - ts;
#pragma unroll
  for (int j = 0; j < 8; ++j) {
    int i = base + j;
    if (i < NSEG) { off[i] = run; cursor[i] = run; }
    run += v[j];
  }
}

// ---- bucket src indices per dst ----
__global__ void k_fill(const int* __restrict__ ab, const int* __restrict__ ba,
                       int* __restrict__ cursor, int* __restrict__ sorted) {
  int stride = gridDim.x * blockDim.x;
  for (int e = blockIdx.x * blockDim.x + threadIdx.x; e < 2 * NEDGE; e += stride) {
    int g, src;
    if (e < NEDGE) { g = NATOMS + ab[NEDGE + e]; src = ab[e]; }
    else { int e2 = e - NEDGE; g = ba[NEDGE + e2]; src = ba[e2]; }
    int pos = atomicAdd(cursor + g, 1);
    sorted[pos] = src;
  }
}

// ---- gather-sum: one wave per dst row, write agg row once ----
__global__ void k_gather(const float* __restrict__ xa, const float* __restrict__ xb,
                         const int* __restrict__ sorted, const int* __restrict__ off,
                         const int* __restrict__ cnt, float* __restrict__ out) {
  int wid = (blockIdx.x * blockDim.x + threadIdx.x) >> 6;
  int lane = threadIdx.x & 63;
  int nw = (gridDim.x * blockDim.x) >> 6;
  for (int g = wid; g < NSEG; g += nw) {
    int start = off[g], deg = cnt[g];
    const float* src = (g < NATOMS) ? xb : xa;   // atom dst <- bond srcs, bond dst <- atom srcs
    float ax = 0.f, ay = 0.f;
    int k = 0;
    for (; k + 1 < deg; k += 2) {
      int s0 = sorted[start + k], s1 = sorted[start + k + 1];
      float2 v0 = *(const float2*)(src + (size_t)s0 * DF + lane * 2);
      float2 v1 = *(const float2*)(src + (size_t)s1 * DF + lane * 2);
      ax += v0.x + v1.x; ay += v0.y + v1.y;
    }
    if (k < deg) {
      int s0 = sorted[start + k];
      float2 v0 = *(const float2*)(src + (size_t)s0 * DF + lane * 2);
      ax += v0.x; ay += v0.y;
    }
    float2 r; r.x = ax; r.y = ay;
    *(float2*)(out + (size_t)g * DF + lane * 2) = r;
  }
}

// ---- fused: out_row = agg@W^T + cnt*b + relu(x@Wr^T + br); BN partial stats ----
__global__ __launch_bounds__(256) void k_gemm(
    const float* __restrict__ xa, const float* __restrict__ xb,
    float* __restrict__ out,
    const int* __restrict__ ca, const int* __restrict__ cb,
    const u16* __restrict__ Wb, const u16* __restrict__ Wrb,
    const float* __restrict__ bb, const float* __restrict__ brb,
    float* __restrict__ stats) {
  __shared__ u16 Wl[DF * DF];    // 32KB, XOR-swizzled by row&7 at 16B granularity
  __shared__ u16 Wrl[DF * DF];   // 32KB

  {
    const uint4* gw  = (const uint4*)Wb;
    const uint4* gwr = (const uint4*)Wrb;
    uint4* lw  = (uint4*)Wl;
    uint4* lwr = (uint4*)Wrl;
    for (int i = threadIdx.x; i < DF * DF / 8; i += 256) {
      int row = i >> 4, c8 = i & 15;
      int dst = (row << 4) | (c8 ^ (row & 7));
      lw[dst]  = gw[i];
      lwr[dst] = gwr[i];
    }
  }
  __syncthreads();

  int typ, base, nrows;
  const float* x; const int* cnt; float* o;
  if ((int)blockIdx.x < NATOMS / 64) {
    typ = 0; base = blockIdx.x * 64; nrows = NATOMS;
    x = xa; cnt = ca; o = out;
  } else {
    typ = 1; base = ((int)blockIdx.x - NATOMS / 64) * 64; nrows = NBONDS;
    x = xb; cnt = cb; o = out + (size_t)NATOMS * DF;
  }

  int lane = threadIdx.x & 63;
  int wv = threadIdx.x >> 6;
  int r16 = lane & 15;
  int kq = lane >> 4;
  int arow = base + wv * 16 + r16;
  bool avalid = arow < nrows;

  f32x4 accW[8], accR[8];
#pragma unroll
  for (int t = 0; t < 8; ++t) {
#pragma unroll
    for (int r = 0; r < 4; ++r) { accW[t][r] = 0.f; accR[t][r] = 0.f; }
  }

  const float* aggp = o + (size_t)arow * DF + kq * 8;
  const float* xp   = x + (size_t)arow * DF + kq * 8;

#pragma unroll
  for (int kk = 0; kk < 4; ++kk) {
    bf16x8 afA = zero8(), afX = zero8();
    if (avalid) {
      const float4 a0 = *(const float4*)(aggp + kk * 32);
      const float4 a1 = *(const float4*)(aggp + kk * 32 + 4);
      const float4 x0 = *(const float4*)(xp + kk * 32);
      const float4 x1 = *(const float4*)(xp + kk * 32 + 4);
      afA[0] = f2b(a0.x); afA[1] = f2b(a0.y); afA[2] = f2b(a0.z); afA[3] = f2b(a0.w);
      afA[4] = f2b(a1.x); afA[5] = f2b(a1.y); afA[6] = f2b(a1.z); afA[7] = f2b(a1.w);
      afX[0] = f2b(x0.x); afX[1] = f2b(x0.y); afX[2] = f2b(x0.z); afX[3] = f2b(x0.w);
      afX[4] = f2b(x1.x); afX[5] = f2b(x1.y); afX[6] = f2b(x1.z); afX[7] = f2b(x1.w);
    }
    int c8 = kk * 4 + kq;
#pragma unroll
    for (int t = 0; t < 8; ++t) {
      int rw = t * 16 + r16;
      int chunk = (rw << 4) | (c8 ^ (rw & 7));
      bf16x8 bW = *(const bf16x8*)(Wl + chunk * 8);
      bf16x8 bR = *(const bf16x8*)(Wrl + chunk * 8);
      accW[t] = __builtin_amdgcn_mfma_f32_16x16x32_bf16(afA, bW, accW[t], 0, 0, 0);
      accR[t] = __builtin_amdgcn_mfma_f32_16x16x32_bf16(afX, bR, accR[t], 0, 0, 0);
    }
  }

  // epilogue: C/D layout col = lane&15, row = (lane>>4)*4 + reg   [m89-verified]
  int orow0 = base + wv * 16 + kq * 4;
  float cf[4];
#pragma unroll
  for (int r = 0; r < 4; ++r) {
    int rr = orow0 + r;
    cf[r] = (rr < nrows) ? (float)cnt[rr] : 0.f;
  }

  float lsum[8], lss[8];
#pragma unroll
  for (int t = 0; t < 8; ++t) {
    int feat = t * 16 + r16;
    float bv = bb[feat], brv = brb[feat];
    float ts = 0.f, tss = 0.f;
#pragma unroll
    for (int r = 0; r < 4; ++r) {
      int rr = orow0 + r;
      if (rr < nrows) {
        float g = accW[t][r] + cf[r] * bv + fmaxf(accR[t][r] + brv, 0.f);
        o[(size_t)rr * DF + feat] = g;
        ts += g; tss += g * g;
      }
    }
    lsum[t] = ts; lss[t] = tss;
  }

  __syncthreads();
  float* s_sum = (float*)Wl;
  float* s_ss  = ((float*)Wl) + DF;
  if (threadIdx.x < DF) { s_sum[threadIdx.x] = 0.f; s_ss[threadIdx.x] = 0.f; }
  __syncthreads();
#pragma unroll
  for (int t = 0; t < 8; ++t) {
    float s = lsum[t], q = lss[t];
    s += __shfl_xor(s, 16); q += __shfl_xor(q, 16);
    s += __shfl_xor(s, 32); q += __shfl_xor(q, 32);
    if (kq == 0) {
      atomicAdd(&s_sum[t * 16 + r16], s);
      atomicAdd(&s_ss[t * 16 + r16], q);
    }
  }
  __syncthreads();
  if (threadIdx.x < DF) {
    float* dstS = stats + ((size_t)(blockIdx.x & (NBUCK - 1)) * 2 + typ) * 2 * DF;
    atomicAdd(dstS + threadIdx.x, s_sum[threadIdx.x]);
    atomicAdd(dstS + DF + threadIdx.x, s_ss[threadIdx.x]);
  }
}

// ---- finalize stats -> scale/shift per (type, feature) ----
__global__ void k_stats(const float* __restrict__ stats,
                        const float* __restrict__ ga, const float* __restrict__ bea,
                        const float* __restrict__ gb, const float* __restrict__ beb,
                        float* __restrict__ scale, float* __restrict__ shift) {
  int tid = threadIdx.x;
  if (tid < 2 * DF) {
    int t = tid >> 7, f = tid & (DF - 1);
    float S = 0.f, SS = 0.f;
    for (int bk = 0; bk < NBUCK; ++bk) {
      const float* p = stats + ((size_t)bk * 2 + t) * 2 * DF;
      S += p[f]; SS += p[DF + f];
    }
    float n = t ? (float)NBONDS : (float)NATOMS;
    float mean = S / n;
    float var = SS / n - mean * mean;
    float rstd = rsqrtf(var + EPS);
    float g = t ? gb[f] : ga[f];
    float be = t ? beb[f] : bea[f];
    scale[tid] = rstd * g;
    shift[tid] = be - mean * rstd * g;
  }
}

// ---- in-place normalize ----
__global__ void k_norm(float* __restrict__ out, const float* __restrict__ scale,
                       const float* __restrict__ shift) {
  const size_t nv = (size_t)(NATOMS + NBONDS) * DF / 4;
  size_t stride = (size_t)gridDim.x * blockDim.x;
  for (size_t i = (size_t)blockIdx.x * blockDim.x + threadIdx.x; i < nv; i += stride) {
    size_t e = i * 4;
    int t = e >= (size_t)NATOMS * DF;
    int f = (int)(e & (DF - 1));
    const float* sc = scale + t * DF + f;
    const float* sh = shift + t * DF + f;
    float4 v = ((float4*)out)[i];
    v.x = fmaf(v.x, sc[0], sh[0]);
    v.y = fmaf(v.y, sc[1], sh[1]);
    v.z = fmaf(v.z, sc[2], sh[2]);
    v.w = fmaf(v.w, sc[3], sh[3]);
    ((float4*)out)[i] = v;
  }
}

extern "C" void kernel_launch(void* const* d_in, const int* in_sizes, int n_in,
                              void* d_out, int out_size, void* d_ws, size_t ws_size,
                              hipStream_t stream) {
  const float* xa  = (const float*)d_in[0];
  const float* xb  = (const float*)d_in[1];
  const int*   ab  = (const int*)d_in[2];
  const int*   ba  = (const int*)d_in[3];
  const float* W   = (const float*)d_in[4];
  const float* b   = (const float*)d_in[5];
  const float* Wr  = (const float*)d_in[6];
  const float* br  = (const float*)d_in[7];
  const float* ga  = (const float*)d_in[8];
  const float* bea = (const float*)d_in[9];
  const float* gb  = (const float*)d_in[10];
  const float* beb = (const float*)d_in[11];
  float* out = (float*)d_out;

  char* ws = (char*)d_ws;
  int*   cnt    = (int*)ws;                     // 2,000,000 B
  int*   off    = (int*)(ws + 2000000);         // 2,000,000 B
  int*   cursor = (int*)(ws + 4000000);         // 2,000,000 B
  int*   sorted = (int*)(ws + 6000000);         // 4,800,000 B
  int*   bsum   = (int*)(ws + 10800000);        // 1,024 B
  int*   bbase  = (int*)(ws + 10801024);        // 1,024 B
  float* stats  = (float*)(ws + 10802048);      // 65,536 B
  u16*   Wbf    = (u16*)(ws + 10867584);        // 32,768 B
  u16*   Wrbf   = (u16*)(ws + 10900352);        // 32,768 B
  float* scale  = (float*)(ws + 10933120);      // 1,024 B
  float* shift  = (float*)(ws + 10934144);      // 1,024 B

  hipMemsetAsync(cnt, 0, 2000000, stream);                      // counts
  hipMemsetAsync(stats, 0, 65536, stream);                      // BN partials

  k_prep<<<64, 256, 0, stream>>>(W, Wr, Wbf, Wrbf);
  k_hist<<<2048, 256, 0, stream>>>(ab, ba, cnt);
  k_scanA<<<NSBLK, 256, 0, stream>>>(cnt, bsum);
  k_scanB<<<1, 256, 0, stream>>>(bsum, bbase);
  k_scanC<<<NSBLK, 256, 0, stream>>>(cnt, bbase, off, cursor);
  k_fill<<<2048, 256, 0, stream>>>(ab, ba, cursor, sorted);
  k_gather<<<8192, 256, 0, stream>>>(xa, xb, sorted, off, cnt, out);
  int nblk = NATOMS / 64 + (NBONDS + 63) / 64;  // 3125 + 4688
  k_gemm<<<nblk, 256, 0, stream>>>(xa, xb, out, cnt, cnt + NATOMS, Wbf, Wrbf, b, br, stats);
  k_stats<<<1, 256, 0, stream>>>(stats, ga, bea, gb, beb, scale, shift);
  k_norm<<<16384, 256, 0, stream>>>(out, scale, shift);
}